// Round 5
// baseline (346.604 us; speedup 1.0000x reference)
//
#include <hip/hip_runtime.h>
#include <math.h>

#define TN 8192
#define AN 128
#define NW20 (TN - 20)   // 8172
#define NW10 (TN - 10)   // 8182

#define NB_GRAM 128
#define NB_ROW  512
#define NB_R20  2043     // 2043*4 = 8172 windows, 1 per wave
#define NB_R10  2046     // 2046*4 = 8184 >= 8182
#define NB_WORK (NB_GRAM + NB_ROW + NB_R20 + NB_R10)   // 4729
#define NB_FOLD 64
#define B_TAIL  (NB_WORK + NB_FOLD)                    // 4793
#define GRID    (B_TAIL + 1)                           // 4794

#define MAGICG 0x5AFE0601u
#define MAGICA 0x5AFE0A01u
#define MAGICB 0x5AFE0B01u

// ---- workspace double-layout ----
#define WS_STD0 0
#define WS_STDL 1
#define WS_SPEC 8                    // 64*3 {sum, sumabs, trace}
#define WS_BLK  200                  // NB_WORK*2 per-block scalar slots
#define WS_DEND 9664

struct __align__(16) SMem {
  union {
    float stage[8][AN];                                        // 4096 B
    struct { double muS[AN], dS[AN]; double fr[4][3]; } fold;  // 2144 B
    struct { float vv[AN], prt[256], un[AN], red[4]; } pi;     // 2064 B
    struct { float f[2 * AN], h1[AN], h2[64], lg[4]; } mlp;    // 1808 B
    struct { double part[4][5]; } scal;                        // 160 B
  } u;
  double tacc[4][5];
  double tiny[8];
};

// rolling off-diag corr via C.sum() = sum_t (sum_i z_ti)^2; butterfly with
// lane-compression (r1-r4 verified, absmax 7e-9). One wave per window.
template <int W>
__device__ __forceinline__ double roll_off(const float* __restrict__ base,
                                           int lane) {
  float x0[W], x1[W];
#pragma unroll
  for (int t = 0; t < W; ++t) {
    x0[t] = base[t * AN + lane];
    x1[t] = base[t * AN + lane + 64];
  }
  float s0 = 0.f, s1 = 0.f;
#pragma unroll
  for (int t = 0; t < W; ++t) { s0 += x0[t]; s1 += x1[t]; }
  float mu0 = s0 / W, mu1 = s1 / W;
  float v0 = 0.f, v1 = 0.f;
#pragma unroll
  for (int t = 0; t < W; ++t) {
    float a = x0[t] - mu0, b = x1[t] - mu1;
    v0 += a * a;
    v1 += b * b;
  }
  float a0 = 1.0f / sqrtf(v0), a1 = 1.0f / sqrtf(v1);
  float q[W];
#pragma unroll
  for (int t = 0; t < W; ++t)
    q[t] = (x0[t] - mu0) * a0 + (x1[t] - mu1) * a1;
  int n = W;
#pragma unroll
  for (int o = 1; o <= 32; o <<= 1) {
#pragma unroll
    for (int k = 0; k < n; ++k) q[k] += __shfl_xor(q[k], o);
    if (n > 1) {
      int nh = n >> 1;
      bool hi = (lane & o) != 0;
#pragma unroll
      for (int k = 0; k < nh; ++k) q[k] = hi ? q[2 * k + 1] : q[2 * k];
      if (n & 1) { q[nh] = q[2 * nh]; n = nh + 1; } else { n = nh; }
    }
  }
  float alpha = (W == 20) ? ((lane & 16) ? 0.125f : 0.5f)
                          : ((lane & 8) ? 0.0625f : 0.25f);
  float r = q[0] * q[0] * alpha;
#pragma unroll
  for (int o = 32; o; o >>= 1) r += __shfl_xor(r, o);
  return ((double)r - (double)AN) / ((double)AN * (AN - 1));
}

__global__ void __launch_bounds__(256) k_all(
    const float* __restrict__ x, const float* __restrict__ pos,
    const float* __restrict__ w1, const float* __restrict__ b1,
    const float* __restrict__ gamma, const float* __restrict__ beta,
    const float* __restrict__ w2, const float* __restrict__ b2,
    const float* __restrict__ w3, const float* __restrict__ b3,
    double* __restrict__ wsd, float* __restrict__ corr,
    float* __restrict__ pc, float* __restrict__ pdg, float* __restrict__ pg,
    unsigned int* __restrict__ flagG, unsigned int* __restrict__ flagA,
    unsigned int* __restrict__ flagB, float* __restrict__ out) {
  __shared__ SMem sm;
  const int b = blockIdx.x;
  const int tid = threadIdx.x;
  const int lane = tid & 63;
  const int w = tid >> 6;

  if (b < NB_GRAM) {
    // =============== gram slice: 64 rows, 8x8 register tiles ===========
    int i0 = (tid >> 4) * 8;
    int j0 = (tid & 15) * 8;
    int lrow = tid >> 5;
    int lcol = (tid & 31) * 4;
    const float* xs = x + (size_t)b * 64 * AN;
    float acc[8][8];
#pragma unroll
    for (int a = 0; a < 8; ++a)
#pragma unroll
      for (int c = 0; c < 8; ++c) acc[a][c] = 0.f;
    float4 v = *(const float4*)(xs + lrow * AN + lcol);
    for (int it = 0; it < 8; ++it) {
      __syncthreads();
      *(float4*)(&sm.u.stage[lrow][lcol]) = v;
      __syncthreads();
      if (it + 1 < 8)
        v = *(const float4*)(xs + ((it + 1) * 8 + lrow) * AN + lcol);
#pragma unroll
      for (int r = 0; r < 8; ++r) {
        float aa[8], bb[8];
        *(float4*)(aa) = *(const float4*)(&sm.u.stage[r][i0]);
        *(float4*)(aa + 4) = *(const float4*)(&sm.u.stage[r][i0 + 4]);
        *(float4*)(bb) = *(const float4*)(&sm.u.stage[r][j0]);
        *(float4*)(bb + 4) = *(const float4*)(&sm.u.stage[r][j0 + 4]);
#pragma unroll
        for (int ai = 0; ai < 8; ++ai)
#pragma unroll
          for (int bj = 0; bj < 8; ++bj)
            acc[ai][bj] = fmaf(aa[ai], bb[bj], acc[ai][bj]);
      }
    }
    float* dst = pg + (size_t)b * (AN * AN);
#pragma unroll
    for (int ai = 0; ai < 8; ++ai)
#pragma unroll
      for (int bj = 0; bj < 8; bj += 4)
        *(float4*)(dst + (i0 + ai) * AN + j0 + bj) =
            make_float4(acc[ai][bj], acc[ai][bj + 1], acc[ai][bj + 2],
                        acc[ai][bj + 3]);
    if ((tid >> 4) == (tid & 15)) {
#pragma unroll
      for (int k = 0; k < 8; ++k) pdg[b * AN + i0 + k] = acc[k][k];
    }
    if (tid < AN) {
      float cs = 0.f;
      for (int r = 0; r < 64; ++r) cs += xs[r * AN + tid];
      pc[b * AN + tid] = cs;
    }
    __syncthreads();
    if (tid == 0) {
      __threadfence();
      __hip_atomic_store(&flagG[b], MAGICG, __ATOMIC_RELEASE,
                         __HIP_MEMORY_SCOPE_AGENT);
      __hip_atomic_store(&flagA[b], MAGICA, __ATOMIC_RELEASE,
                         __HIP_MEMORY_SCOPE_AGENT);
    }
    return;
  }

  if (b < NB_GRAM + NB_ROW) {
    // ========== per-row std + sign counts, 16 rows/block ===============
    int rb = b - NB_GRAM;
    double sstd = 0.0, sconc = 0.0;
    for (int rr = 0; rr < 4; ++rr) {
      int t = rb * 16 + w * 4 + rr;
      const float* row = x + (size_t)t * AN;
      float x0 = row[lane], x1 = row[lane + 64];
      float s = x0 + x1;
#pragma unroll
      for (int o = 32; o; o >>= 1) s += __shfl_xor(s, o);
      float mean = s * (1.0f / AN);
      float d0 = x0 - mean, d1 = x1 - mean;
      float q = d0 * d0 + d1 * d1;
#pragma unroll
      for (int o = 32; o; o >>= 1) q += __shfl_xor(q, o);
      float sd = sqrtf(q / (float)(AN - 1));
      int pk = (int)(x0 < 0.f) + (int)(x1 < 0.f)
             + (((int)(x0 == 0.f) + (int)(x1 == 0.f)) << 10)
             + (((int)(x0 > 0.f) + (int)(x1 > 0.f)) << 20);
#pragma unroll
      for (int o = 32; o; o >>= 1) pk += __shfl_xor(pk, o);
      if (lane == 0) {
        int nn = pk & 1023, nz = (pk >> 10) & 1023, np = (pk >> 20) & 1023;
        sconc += (double)nn * nn + (double)nz * nz + (double)np * np;
        sstd += (double)sd;
        if (t == 0) wsd[WS_STD0] = (double)sd;
        if (t == TN - 1) wsd[WS_STDL] = (double)sd;
      }
    }
    if (lane == 0) { sm.tacc[w][0] = sstd; sm.tacc[w][1] = sconc; }
    __syncthreads();
    if (tid == 0) {
      wsd[WS_BLK + (size_t)b * 2 + 0] =
          sm.tacc[0][0] + sm.tacc[1][0] + sm.tacc[2][0] + sm.tacc[3][0];
      wsd[WS_BLK + (size_t)b * 2 + 1] =
          sm.tacc[0][1] + sm.tacc[1][1] + sm.tacc[2][1] + sm.tacc[3][1];
      __threadfence();
      __hip_atomic_store(&flagA[b], MAGICA, __ATOMIC_RELEASE,
                         __HIP_MEMORY_SCOPE_AGENT);
    }
    return;
  }

  if (b < NB_GRAM + NB_ROW + NB_R20) {
    // ================ roll20: one window per wave ======================
    int s = (b - (NB_GRAM + NB_ROW)) * 4 + w;
    double cnt = 0.0;
    if (s < NW20) {
      double off = roll_off<20>(x + (size_t)s * AN, lane);
      if (lane == 0) cnt = (off > 0.7) ? 1.0 : 0.0;
    }
    if (lane == 0) sm.tacc[w][0] = cnt;
    __syncthreads();
    if (tid == 0) {
      wsd[WS_BLK + (size_t)b * 2 + 0] =
          sm.tacc[0][0] + sm.tacc[1][0] + sm.tacc[2][0] + sm.tacc[3][0];
      __threadfence();
      __hip_atomic_store(&flagA[b], MAGICA, __ATOMIC_RELEASE,
                         __HIP_MEMORY_SCOPE_AGENT);
    }
    return;
  }

  if (b < NB_WORK) {
    // ================ roll10: one window per wave ======================
    int s = (b - (NB_GRAM + NB_ROW + NB_R20)) * 4 + w;
    double s10 = 0.0, s10l5 = 0.0;
    if (s < NW10) {
      double off = roll_off<10>(x + (size_t)s * AN, lane);
      if (lane == 0) {
        s10 = off;
        if (s >= TN - 10 - 5) s10l5 = off;
      }
    }
    if (lane == 0) { sm.tacc[w][0] = s10; sm.tacc[w][1] = s10l5; }
    __syncthreads();
    if (tid == 0) {
      wsd[WS_BLK + (size_t)b * 2 + 0] =
          sm.tacc[0][0] + sm.tacc[1][0] + sm.tacc[2][0] + sm.tacc[3][0];
      wsd[WS_BLK + (size_t)b * 2 + 1] =
          sm.tacc[0][1] + sm.tacc[1][1] + sm.tacc[2][1] + sm.tacc[3][1];
      __threadfence();
      __hip_atomic_store(&flagA[b], MAGICA, __ATOMIC_RELEASE,
                         __HIP_MEMORY_SCOPE_AGENT);
    }
    return;
  }

  if (b < B_TAIL) {
    // ============== fold: cov -> corr + spec partials ==================
    const int c = b - NB_WORK;
    if (tid < NB_GRAM) {
      while (__hip_atomic_load(&flagG[tid], __ATOMIC_ACQUIRE,
                               __HIP_MEMORY_SCOPE_AGENT) != MAGICG)
        __builtin_amdgcn_s_sleep(4);
    }
    __syncthreads();
    __threadfence();
    if (tid < AN) {
      double cs = 0.0, dg = 0.0;
      for (int s = 0; s < NB_GRAM; ++s) {
        cs += (double)pc[s * AN + tid];
        dg += (double)pdg[s * AN + tid];
      }
      double mu = cs / (double)TN;
      sm.u.fold.muS[tid] = mu;
      sm.u.fold.dS[tid] = sqrt(dg - (double)TN * mu * mu);
    }
    __syncthreads();
    int e = c * 256 + tid;
    int i = e >> 7, j = e & (AN - 1);
    double cv = 0.0;
    for (int s = 0; s < NB_GRAM; ++s) cv += (double)pg[(size_t)s * (AN * AN) + e];
    cv -= (double)TN * sm.u.fold.muS[i] * sm.u.fold.muS[j];
    double cc = cv / (sm.u.fold.dS[i] * sm.u.fold.dS[j]);
    corr[e] = (float)cc;
    double c0 = cc, c1 = fabs(cc), c2 = (i == j) ? cc : 0.0;
#pragma unroll
    for (int o = 32; o; o >>= 1) {
      c0 += __shfl_xor(c0, o);
      c1 += __shfl_xor(c1, o);
      c2 += __shfl_xor(c2, o);
    }
    if (lane == 0) {
      sm.u.fold.fr[w][0] = c0;
      sm.u.fold.fr[w][1] = c1;
      sm.u.fold.fr[w][2] = c2;
    }
    __syncthreads();
    if (tid == 0) {
#pragma unroll
      for (int k = 0; k < 3; ++k)
        wsd[WS_SPEC + c * 3 + k] = sm.u.fold.fr[0][k] + sm.u.fold.fr[1][k] +
                                   sm.u.fold.fr[2][k] + sm.u.fold.fr[3][k];
      __threadfence();
      __hip_atomic_store(&flagB[c], MAGICB, __ATOMIC_RELEASE,
                         __HIP_MEMORY_SCOPE_AGENT);
    }
    return;
  }

  // ===================== tail block (b == B_TAIL) ======================
  for (int k = tid; k < NB_WORK; k += 256) {
    while (__hip_atomic_load(&flagA[k], __ATOMIC_ACQUIRE,
                             __HIP_MEMORY_SCOPE_AGENT) != MAGICA)
      __builtin_amdgcn_s_sleep(4);
  }
  if (tid < NB_FOLD) {
    while (__hip_atomic_load(&flagB[tid], __ATOMIC_ACQUIRE,
                             __HIP_MEMORY_SCOPE_AGENT) != MAGICB)
      __builtin_amdgcn_s_sleep(4);
  }
  __syncthreads();
  __threadfence();
  // scalar folds over per-block slots
  {
    double v0 = 0, v1 = 0, v2 = 0, v3 = 0, v4 = 0;
    for (int k = tid; k < NB_WORK; k += 256) {
      if (k < NB_GRAM) continue;
      const double* p = wsd + WS_BLK + (size_t)k * 2;
      if (k < NB_GRAM + NB_ROW) { v0 += p[0]; v1 += p[1]; }
      else if (k < NB_GRAM + NB_ROW + NB_R20) v2 += p[0];
      else { v3 += p[0]; v4 += p[1]; }
    }
#pragma unroll
    for (int o = 32; o; o >>= 1) {
      v0 += __shfl_xor(v0, o); v1 += __shfl_xor(v1, o);
      v2 += __shfl_xor(v2, o); v3 += __shfl_xor(v3, o);
      v4 += __shfl_xor(v4, o);
    }
    if (lane == 0) {
      sm.u.scal.part[w][0] = v0; sm.u.scal.part[w][1] = v1;
      sm.u.scal.part[w][2] = v2; sm.u.scal.part[w][3] = v3;
      sm.u.scal.part[w][4] = v4;
    }
    __syncthreads();
    if (tid == 0) {
#pragma unroll
      for (int k = 0; k < 5; ++k)
        sm.tiny[k] = sm.u.scal.part[0][k] + sm.u.scal.part[1][k] +
                     sm.u.scal.part[2][k] + sm.u.scal.part[3][k];
    }
    __syncthreads();
  }
  {
    double v0 = 0, v1 = 0, v2 = 0;
    if (tid < NB_FOLD) {
      v0 = wsd[WS_SPEC + tid * 3 + 0];
      v1 = wsd[WS_SPEC + tid * 3 + 1];
      v2 = wsd[WS_SPEC + tid * 3 + 2];
    }
    if (tid < 64) {
#pragma unroll
      for (int o = 32; o; o >>= 1) {
        v0 += __shfl_xor(v0, o);
        v1 += __shfl_xor(v1, o);
        v2 += __shfl_xor(v2, o);
      }
      if (tid == 0) { sm.tiny[5] = v0; sm.tiny[6] = v1; sm.tiny[7] = v2; }
    }
    __syncthreads();
  }
  // power iteration on corr (L2-hot), 3 barriers/iter
  if (tid < AN) sm.u.pi.vv[tid] = 1.0f;
  __syncthreads();
  int ri = tid & (AN - 1), hh = tid >> 7;
  const float4* rp = (const float4*)(corr + ri * AN + hh * 64);
  float lam = 0.0f;
  for (int it = 0; it < 12; ++it) {
    const float4* vp = (const float4*)(&sm.u.pi.vv[hh * 64]);
    float acc = 0.f;
#pragma unroll
    for (int k = 0; k < 16; ++k) {
      float4 a = rp[k], bv = vp[k];
      acc += a.x * bv.x + a.y * bv.y + a.z * bv.z + a.w * bv.w;
    }
    sm.u.pi.prt[tid] = acc;
    __syncthreads();
    if (tid < AN) {
      float u = sm.u.pi.prt[tid] + sm.u.pi.prt[tid + 128];
      sm.u.pi.un[tid] = u;
      float sq = u * u;
#pragma unroll
      for (int o = 32; o; o >>= 1) sq += __shfl_xor(sq, o);
      if (lane == 0) sm.u.pi.red[w] = sq;
    }
    __syncthreads();
    lam = sqrtf(sm.u.pi.red[0] + sm.u.pi.red[1]);
    if (tid < AN) sm.u.pi.vv[tid] = sm.u.pi.un[tid] / lam;
    __syncthreads();
  }
  __syncthreads();
  // MLP
  sm.u.mlp.f[tid] = (tid < AN) ? x[(size_t)(TN - 1) * AN + tid] : pos[tid - AN];
  __syncthreads();
  if (tid < AN) {
    float acc = b1[tid];
    for (int k = 0; k < 2 * AN; ++k)
      acc = fmaf(sm.u.mlp.f[k], w1[k * AN + tid], acc);
    acc = fmaxf(acc, 0.0f);
    acc = gamma[tid] * (acc / sqrtf(1.0f + 1e-5f)) + beta[tid];
    sm.u.mlp.h1[tid] = acc;
  }
  __syncthreads();
  if (tid < 64) {
    float acc = b2[tid];
    for (int k = 0; k < AN; ++k)
      acc = fmaf(sm.u.mlp.h1[k], w2[k * 64 + tid], acc);
    sm.u.mlp.h2[tid] = fmaxf(acc, 0.0f);
  }
  __syncthreads();
  if (tid < 3) {
    float acc = b3[tid];
    for (int k = 0; k < 64; ++k)
      acc = fmaf(sm.u.mlp.h2[k], w3[k * 3 + tid], acc);
    sm.u.mlp.lg[tid] = acc;
  }
  __syncthreads();
  if (tid != 0) return;
  float m = fmaxf(sm.u.mlp.lg[0], fmaxf(sm.u.mlp.lg[1], sm.u.mlp.lg[2]));
  float e0 = expf(sm.u.mlp.lg[0] - m), e1 = expf(sm.u.mlp.lg[1] - m),
        e2 = expf(sm.u.mlp.lg[2] - m);
  double sev = (double)(e2 / (e0 + e1 + e2));
  double sumstd = sm.tiny[0], conc = sm.tiny[1], cnt20 = sm.tiny[2];
  double sum10 = sm.tiny[3], sum10l5 = sm.tiny[4];
  double csum = sm.tiny[5], cabs = sm.tiny[6], ctrace = sm.tiny[7];
  double avg_disp = sumstd / (double)TN;
  double trend = -(wsd[WS_STDL] - wsd[WS_STD0]) / (double)(TN - 1);
  double hi = trend / (avg_disp + 1e-6) + 0.5;
  hi = fmin(1.0, fmax(0.0, hi));
  double avg_corr = (csum - ctrace) / ((double)AN * (AN - 1));
  double sync_ind = (double)lam / (double)AN;
  double sync_risk = fmin(1.0, sync_ind * avg_corr);
  double pl = cnt20 / (double)(TN - 20);
  double rd = 1.0 - cabs / ((double)AN * AN);
  double pasum = 0.0, pamax = 0.0;
  for (int k = 0; k < AN; ++k) {
    double pa = fabs((double)pos[k]);
    pasum += pa;
    if (pa > pamax) pamax = pa;
  }
  double pd = 1.0 - pamax / pasum;
  double dl = 1.0 - sqrt(rd * pd);
  double recent = sum10l5 / 5.0;
  double hist = (sum10 - sum10l5) / (double)(TN - 10 - 5);
  double sraw = (recent - hist) / hist;
  sraw = fmin(1.0, fmax(0.0, sraw));
  double surge = (hist > 0.0) ? sraw : 0.0;
  double ac = (conc / (double)TN - (double)AN) / ((double)AN * (AN - 1));
  double pcup = fmin(1.0, fmax(0.0, (ac - 0.5) * 2.0));
  double cr = (hi + sync_risk + dl) / 3.0;
  out[0] = (float)hi;
  out[1] = (float)sev;
  out[2] = (float)sync_risk;
  out[3] = (float)pl;
  out[4] = (float)dl;
  out[5] = (float)surge;
  out[6] = (float)pcup;
  out[7] = (float)cr;
}

extern "C" void kernel_launch(void* const* d_in, const int* in_sizes, int n_in,
                              void* d_out, int out_size, void* d_ws, size_t ws_size,
                              hipStream_t stream) {
  const float* x     = (const float*)d_in[0];
  const float* pos   = (const float*)d_in[1];
  const float* w1    = (const float*)d_in[2];
  const float* b1    = (const float*)d_in[3];
  const float* gamma = (const float*)d_in[4];
  const float* beta  = (const float*)d_in[5];
  const float* w2    = (const float*)d_in[6];
  const float* b2    = (const float*)d_in[7];
  const float* w3    = (const float*)d_in[8];
  const float* b3    = (const float*)d_in[9];
  float* out = (float*)d_out;
  double* wsd = (double*)d_ws;
  float* corr = (float*)(wsd + WS_DEND);               // [16384]
  float* pc   = corr + AN * AN;                        // [128*128]
  float* pdg  = pc + NB_GRAM * AN;                     // [128*128]
  float* pg   = pdg + NB_GRAM * AN;                    // [128*16384]
  unsigned int* flagG = (unsigned int*)(pg + (size_t)NB_GRAM * AN * AN);
  unsigned int* flagA = flagG + NB_GRAM;
  unsigned int* flagB = flagA + NB_WORK;

  k_all<<<GRID, 256, 0, stream>>>(x, pos, w1, b1, gamma, beta, w2, b2, w3, b3,
                                  wsd, corr, pc, pdg, pg, flagG, flagA, flagB,
                                  out);
}

// Round 6
// 125.617 us; speedup vs baseline: 2.7592x; 2.7592x over previous
//
#include <hip/hip_runtime.h>
#include <math.h>

#define TN 8192
#define AN 128
#define NW20 (TN - 20)   // 8172
#define NW10 (TN - 10)   // 8182

// ---- k_main grid ranges ----
#define NB_GRAM 128
#define NB_ROW  512      // 16 rows/block
#define NB_R20  511      // 16 windows/block (4 waves x strip of 4)
#define NB_R10  512
#define NB_WORK (NB_GRAM + NB_ROW + NB_R20 + NB_R10)   // 1663

// ---- workspace double-layout ----
#define WS_STD0 0
#define WS_STDL 1
#define WS_SPEC 8                    // 64*3 {sum, sumabs, trace}
#define WS_BLK  200                  // NB_WORK*2 per-block scalar slots
#define WS_DEND 4096

// rolling off-diag corr via C.sum() = sum_t (sum_i z_ti)^2; butterfly with
// lane-compression; 4 consecutive windows per wave from one register strip.
// Math verified in R4 (absmax 7.45e-9). Lane owns columns {2*lane, 2*lane+1}
// (column permutation is neutral: all reductions are symmetric over columns).
template <int W>
__device__ __forceinline__ void roll_strip4(const float* __restrict__ x,
                                            int s0, int nwin, int lane,
                                            double& accA, double& accB) {
  constexpr int NR = W + 3;
  float a0[NR], a1[NR];
#pragma unroll
  for (int t = 0; t < NR; ++t) {
    int r = s0 + t; r = (r < TN) ? r : (TN - 1);
    float2 v = *(const float2*)(x + (size_t)r * AN + 2 * lane);
    a0[t] = v.x; a1[t] = v.y;
  }
#pragma unroll
  for (int w4 = 0; w4 < 4; ++w4) {
    int s = s0 + w4;
    if (s < nwin) {
      float sf0 = 0.f, sf1 = 0.f;
#pragma unroll
      for (int t = 0; t < W; ++t) { sf0 += a0[w4 + t]; sf1 += a1[w4 + t]; }
      float mu0 = sf0 / W, mu1 = sf1 / W;
      float v0 = 0.f, v1 = 0.f;
#pragma unroll
      for (int t = 0; t < W; ++t) {
        float d0 = a0[w4 + t] - mu0, d1 = a1[w4 + t] - mu1;
        v0 += d0 * d0; v1 += d1 * d1;
      }
      float i0 = 1.0f / sqrtf(v0), i1 = 1.0f / sqrtf(v1);
      float q[W];
#pragma unroll
      for (int t = 0; t < W; ++t)
        q[t] = (a0[w4 + t] - mu0) * i0 + (a1[w4 + t] - mu1) * i1;
      int n = W;
#pragma unroll
      for (int o = 1; o <= 32; o <<= 1) {
#pragma unroll
        for (int k = 0; k < n; ++k) q[k] += __shfl_xor(q[k], o);
        if (n > 1) {
          int nh = n >> 1;
          bool hi = (lane & o) != 0;
#pragma unroll
          for (int k = 0; k < nh; ++k) q[k] = hi ? q[2 * k + 1] : q[2 * k];
          if (n & 1) { q[nh] = q[2 * nh]; n = nh + 1; } else { n = nh; }
        }
      }
      float alpha = (W == 20) ? ((lane & 16) ? 0.125f : 0.5f)
                              : ((lane & 8) ? 0.0625f : 0.25f);
      float r = q[0] * q[0] * alpha;
#pragma unroll
      for (int o = 32; o; o >>= 1) r += __shfl_xor(r, o);
      if (lane == 0) {
        double off = ((double)r - (double)AN) / ((double)AN * (AN - 1));
        if (W == 20) {
          accA += (off > 0.7) ? 1.0 : 0.0;
        } else {
          accA += off;
          if (s >= TN - W - 5) accB += off;
        }
      }
    }
  }
}

// ============ phase A: all data-parallel work, deterministic slots =======
__global__ void __launch_bounds__(256) k_main(const float* __restrict__ x,
                                              double* __restrict__ wsd,
                                              float* __restrict__ pc,
                                              float* __restrict__ pdg,
                                              float* __restrict__ pg) {
  __shared__ union {
    float stage[8][AN];
    double tacc[4][2];
  } sm;
  const int b = blockIdx.x;
  const int tid = threadIdx.x;
  const int lane = tid & 63;
  const int w = tid >> 6;

  if (b < NB_GRAM) {
    // ---- gram slice: 64 rows, 8x8 register tiles (R1-R5 verified) ----
    int i0 = (tid >> 4) * 8;
    int j0 = (tid & 15) * 8;
    int lrow = tid >> 5;
    int lcol = (tid & 31) * 4;
    const float* xs = x + (size_t)b * 64 * AN;
    float acc[8][8];
#pragma unroll
    for (int a = 0; a < 8; ++a)
#pragma unroll
      for (int c = 0; c < 8; ++c) acc[a][c] = 0.f;
    float4 v = *(const float4*)(xs + lrow * AN + lcol);
    for (int it = 0; it < 8; ++it) {
      __syncthreads();
      *(float4*)(&sm.stage[lrow][lcol]) = v;
      __syncthreads();
      if (it + 1 < 8)
        v = *(const float4*)(xs + ((it + 1) * 8 + lrow) * AN + lcol);
#pragma unroll
      for (int r = 0; r < 8; ++r) {
        float aa[8], bb[8];
        *(float4*)(aa) = *(const float4*)(&sm.stage[r][i0]);
        *(float4*)(aa + 4) = *(const float4*)(&sm.stage[r][i0 + 4]);
        *(float4*)(bb) = *(const float4*)(&sm.stage[r][j0]);
        *(float4*)(bb + 4) = *(const float4*)(&sm.stage[r][j0 + 4]);
#pragma unroll
        for (int ai = 0; ai < 8; ++ai)
#pragma unroll
          for (int bj = 0; bj < 8; ++bj)
            acc[ai][bj] = fmaf(aa[ai], bb[bj], acc[ai][bj]);
      }
    }
    float* dst = pg + (size_t)b * (AN * AN);
#pragma unroll
    for (int ai = 0; ai < 8; ++ai)
#pragma unroll
      for (int bj = 0; bj < 8; bj += 4)
        *(float4*)(dst + (i0 + ai) * AN + j0 + bj) =
            make_float4(acc[ai][bj], acc[ai][bj + 1], acc[ai][bj + 2],
                        acc[ai][bj + 3]);
    if ((tid >> 4) == (tid & 15)) {
#pragma unroll
      for (int k = 0; k < 8; ++k) pdg[b * AN + i0 + k] = acc[k][k];
    }
    if (tid < AN) {
      float cs = 0.f;
      for (int r = 0; r < 64; ++r) cs += xs[r * AN + tid];
      pc[b * AN + tid] = cs;
    }
    return;
  }

  if (b < NB_GRAM + NB_ROW) {
    // ---- per-row std + sign counts, 16 rows/block, float2 cols ----
    int rb = b - NB_GRAM;
    double sstd = 0.0, sconc = 0.0;
    for (int rr = 0; rr < 4; ++rr) {
      int t = rb * 16 + w * 4 + rr;
      float2 xv = *(const float2*)(x + (size_t)t * AN + 2 * lane);
      float x0 = xv.x, x1 = xv.y;
      float s = x0 + x1;
#pragma unroll
      for (int o = 32; o; o >>= 1) s += __shfl_xor(s, o);
      float mean = s * (1.0f / AN);
      float d0 = x0 - mean, d1 = x1 - mean;
      float q = d0 * d0 + d1 * d1;
#pragma unroll
      for (int o = 32; o; o >>= 1) q += __shfl_xor(q, o);
      float sd = sqrtf(q / (float)(AN - 1));
      int pk = (int)(x0 < 0.f) + (int)(x1 < 0.f)
             + (((int)(x0 == 0.f) + (int)(x1 == 0.f)) << 10)
             + (((int)(x0 > 0.f) + (int)(x1 > 0.f)) << 20);
#pragma unroll
      for (int o = 32; o; o >>= 1) pk += __shfl_xor(pk, o);
      if (lane == 0) {
        int nn = pk & 1023, nz = (pk >> 10) & 1023, np = (pk >> 20) & 1023;
        sconc += (double)nn * nn + (double)nz * nz + (double)np * np;
        sstd += (double)sd;
        if (t == 0) wsd[WS_STD0] = (double)sd;
        if (t == TN - 1) wsd[WS_STDL] = (double)sd;
      }
    }
    if (lane == 0) { sm.tacc[w][0] = sstd; sm.tacc[w][1] = sconc; }
    __syncthreads();
    if (tid == 0) {
      wsd[WS_BLK + (size_t)b * 2 + 0] =
          sm.tacc[0][0] + sm.tacc[1][0] + sm.tacc[2][0] + sm.tacc[3][0];
      wsd[WS_BLK + (size_t)b * 2 + 1] =
          sm.tacc[0][1] + sm.tacc[1][1] + sm.tacc[2][1] + sm.tacc[3][1];
    }
    return;
  }

  if (b < NB_GRAM + NB_ROW + NB_R20) {
    int s0 = (b - (NB_GRAM + NB_ROW)) * 16 + w * 4;
    double cnt = 0.0, dummy = 0.0;
    roll_strip4<20>(x, s0, NW20, lane, cnt, dummy);
    if (lane == 0) { sm.tacc[w][0] = cnt; }
    __syncthreads();
    if (tid == 0)
      wsd[WS_BLK + (size_t)b * 2 + 0] =
          sm.tacc[0][0] + sm.tacc[1][0] + sm.tacc[2][0] + sm.tacc[3][0];
    return;
  }

  {
    int s0 = (b - (NB_GRAM + NB_ROW + NB_R20)) * 16 + w * 4;
    double s10 = 0.0, s10l5 = 0.0;
    roll_strip4<10>(x, s0, NW10, lane, s10, s10l5);
    if (lane == 0) { sm.tacc[w][0] = s10; sm.tacc[w][1] = s10l5; }
    __syncthreads();
    if (tid == 0) {
      wsd[WS_BLK + (size_t)b * 2 + 0] =
          sm.tacc[0][0] + sm.tacc[1][0] + sm.tacc[2][0] + sm.tacc[3][0];
      wsd[WS_BLK + (size_t)b * 2 + 1] =
          sm.tacc[0][1] + sm.tacc[1][1] + sm.tacc[2][1] + sm.tacc[3][1];
    }
  }
}

// ====== phase B: fold partials -> cov -> corr + scalar folds (R3) ========
__global__ void __launch_bounds__(256) k_fold(const float* __restrict__ pc,
                                              const float* __restrict__ pdg,
                                              const float* __restrict__ pg,
                                              double* __restrict__ wsd,
                                              float* __restrict__ corr) {
  __shared__ double r0[256], r1[256], r2[256], r3[256], r4[256];
  int b = blockIdx.x;
  int t = threadIdx.x;
  if (b < 64) {
    __shared__ double muS[AN], dS[AN];
    if (t < AN) {
      double cs = 0.0, dg = 0.0;
      for (int s = 0; s < NB_GRAM; ++s) {
        cs += (double)pc[s * AN + t];
        dg += (double)pdg[s * AN + t];
      }
      double mu = cs / (double)TN;
      muS[t] = mu;
      dS[t] = sqrt(dg - (double)TN * mu * mu);
    }
    __syncthreads();
    int e = b * 256 + t;
    int i = e >> 7, j = e & (AN - 1);
    double cv = 0.0;
    for (int s = 0; s < NB_GRAM; ++s) cv += (double)pg[(size_t)s * (AN * AN) + e];
    cv -= (double)TN * muS[i] * muS[j];
    double c = cv / (dS[i] * dS[j]);
    corr[e] = (float)c;
    r0[t] = c;
    r1[t] = fabs(c);
    r2[t] = (i == j) ? c : 0.0;
    __syncthreads();
    for (int sft = 128; sft; sft >>= 1) {
      if (t < sft) { r0[t] += r0[t + sft]; r1[t] += r1[t + sft]; r2[t] += r2[t + sft]; }
      __syncthreads();
    }
    if (t == 0) {
      wsd[WS_SPEC + b * 3 + 0] = r0[0];
      wsd[WS_SPEC + b * 3 + 1] = r1[0];
      wsd[WS_SPEC + b * 3 + 2] = r2[0];
    }
  } else {
    double a = 0.0, bc = 0.0, cnt = 0.0, s10 = 0.0, s10l5 = 0.0;
    for (int k = NB_GRAM + t; k < NB_WORK; k += 256) {
      const double* p = wsd + WS_BLK + (size_t)k * 2;
      if (k < NB_GRAM + NB_ROW) { a += p[0]; bc += p[1]; }
      else if (k < NB_GRAM + NB_ROW + NB_R20) cnt += p[0];
      else { s10 += p[0]; s10l5 += p[1]; }
    }
    r0[t] = a; r1[t] = bc; r2[t] = cnt; r3[t] = s10; r4[t] = s10l5;
    __syncthreads();
    for (int sft = 128; sft; sft >>= 1) {
      if (t < sft) {
        r0[t] += r0[t + sft]; r1[t] += r1[t + sft]; r2[t] += r2[t + sft];
        r3[t] += r3[t + sft]; r4[t] += r4[t + sft];
      }
      __syncthreads();
    }
    if (t == 0) {
      wsd[2] = r0[0];   // sumstd
      wsd[3] = r1[0];   // conc
      wsd[4] = r2[0];   // cnt20
      wsd[5] = r3[0];   // sum10
      wsd[6] = r4[0];   // sum10l5
    }
  }
}

// ====== phase C: power iteration + MLP + assembly (single block) =========
__global__ void __launch_bounds__(256) k_spec_tail(
    const float* __restrict__ x, const float* __restrict__ pos,
    const float* __restrict__ w1, const float* __restrict__ b1,
    const float* __restrict__ gamma, const float* __restrict__ beta,
    const float* __restrict__ w2, const float* __restrict__ b2,
    const float* __restrict__ w3, const float* __restrict__ b3,
    const double* __restrict__ wsd, const float* __restrict__ corr,
    float* __restrict__ out) {
  __shared__ float vv[AN], prt[256], un[AN], red[4];
  __shared__ double spec[3];
  __shared__ float f[2 * AN], h1[AN], h2[64], lg[3];
  int t = threadIdx.x;
  int lane = t & 63;
  int w = t >> 6;
  if (t < 64) {                       // wave 0: fold spec partials
    double s0 = wsd[WS_SPEC + t * 3 + 0];
    double s1 = wsd[WS_SPEC + t * 3 + 1];
    double s2 = wsd[WS_SPEC + t * 3 + 2];
#pragma unroll
    for (int o = 32; o; o >>= 1) {
      s0 += __shfl_xor(s0, o);
      s1 += __shfl_xor(s1, o);
      s2 += __shfl_xor(s2, o);
    }
    if (t == 0) { spec[0] = s0; spec[1] = s1; spec[2] = s2; }
  }
  f[t] = (t < AN) ? x[(size_t)(TN - 1) * AN + t] : pos[t - AN];
  if (t < AN) vv[t] = 1.0f;
  __syncthreads();
  // ---- power iteration, 12 iters, corr L2-hot ----
  int ri = t & (AN - 1), hh = t >> 7;
  const float4* rp = (const float4*)(corr + ri * AN + hh * 64);
  float lam = 0.0f;
  for (int it = 0; it < 12; ++it) {
    const float4* vp = (const float4*)(&vv[hh * 64]);
    float acc = 0.f;
#pragma unroll
    for (int k = 0; k < 16; ++k) {
      float4 a = rp[k], bv = vp[k];
      acc += a.x * bv.x + a.y * bv.y + a.z * bv.z + a.w * bv.w;
    }
    prt[t] = acc;
    __syncthreads();
    if (t < AN) {
      float u = prt[t] + prt[t + 128];
      un[t] = u;
      float sq = u * u;
#pragma unroll
      for (int o = 32; o; o >>= 1) sq += __shfl_xor(sq, o);
      if (lane == 0) red[w] = sq;
    }
    __syncthreads();
    lam = sqrtf(red[0] + red[1]);
    if (t < AN) vv[t] = un[t] / lam;
    __syncthreads();
  }
  // ---- MLP: layer 1 split over 2 half-K groups ----
  {
    int n = t & 127, h = t >> 7;
    float acc = 0.f;
    const float* wcol = w1 + h * 128 * AN + n;
    const float* fv = f + h * 128;
    for (int k = 0; k < 128; ++k) acc = fmaf(fv[k], wcol[k * AN], acc);
    prt[t] = acc;
  }
  __syncthreads();
  if (t < AN) {
    float acc = b1[t] + prt[t] + prt[t + 128];
    acc = fmaxf(acc, 0.0f);
    h1[t] = gamma[t] * (acc / sqrtf(1.0f + 1e-5f)) + beta[t];
  }
  __syncthreads();
  if (t < 64) {
    float acc = b2[t];
    for (int k = 0; k < AN; ++k) acc = fmaf(h1[k], w2[k * 64 + t], acc);
    h2[t] = fmaxf(acc, 0.0f);
  }
  __syncthreads();
  if (t < 3) {
    float acc = b3[t];
    for (int k = 0; k < 64; ++k) acc = fmaf(h2[k], w3[k * 3 + t], acc);
    lg[t] = acc;
  }
  __syncthreads();
  if (t != 0) return;
  float m = fmaxf(lg[0], fmaxf(lg[1], lg[2]));
  float e0 = expf(lg[0] - m), e1 = expf(lg[1] - m), e2 = expf(lg[2] - m);
  double sev = (double)(e2 / (e0 + e1 + e2));
  double sumstd = wsd[2], conc = wsd[3], cnt20 = wsd[4];
  double sum10 = wsd[5], sum10l5 = wsd[6];
  double avg_disp = sumstd / (double)TN;
  double trend = -(wsd[WS_STDL] - wsd[WS_STD0]) / (double)(TN - 1);
  double hi = trend / (avg_disp + 1e-6) + 0.5;
  hi = fmin(1.0, fmax(0.0, hi));
  double avg_corr = (spec[0] - spec[2]) / ((double)AN * (AN - 1));
  double sync_ind = (double)lam / (double)AN;
  double sync_risk = fmin(1.0, sync_ind * avg_corr);
  double pl = cnt20 / (double)(TN - 20);
  double rd = 1.0 - spec[1] / ((double)AN * AN);
  double pasum = 0.0, pamax = 0.0;
  for (int k = 0; k < AN; ++k) {
    double pa = fabs((double)pos[k]);
    pasum += pa;
    if (pa > pamax) pamax = pa;
  }
  double pd = 1.0 - pamax / pasum;
  double dl = 1.0 - sqrt(rd * pd);
  double recent = sum10l5 / 5.0;
  double hist = (sum10 - sum10l5) / (double)(TN - 10 - 5);
  double sraw = (recent - hist) / hist;
  sraw = fmin(1.0, fmax(0.0, sraw));
  double surge = (hist > 0.0) ? sraw : 0.0;
  double ac = (conc / (double)TN - (double)AN) / ((double)AN * (AN - 1));
  double pcup = fmin(1.0, fmax(0.0, (ac - 0.5) * 2.0));
  double cr = (hi + sync_risk + dl) / 3.0;
  out[0] = (float)hi;
  out[1] = (float)sev;
  out[2] = (float)sync_risk;
  out[3] = (float)pl;
  out[4] = (float)dl;
  out[5] = (float)surge;
  out[6] = (float)pcup;
  out[7] = (float)cr;
}

extern "C" void kernel_launch(void* const* d_in, const int* in_sizes, int n_in,
                              void* d_out, int out_size, void* d_ws, size_t ws_size,
                              hipStream_t stream) {
  const float* x     = (const float*)d_in[0];
  const float* pos   = (const float*)d_in[1];
  const float* w1    = (const float*)d_in[2];
  const float* b1    = (const float*)d_in[3];
  const float* gamma = (const float*)d_in[4];
  const float* beta  = (const float*)d_in[5];
  const float* w2    = (const float*)d_in[6];
  const float* b2    = (const float*)d_in[7];
  const float* w3    = (const float*)d_in[8];
  const float* b3    = (const float*)d_in[9];
  float* out = (float*)d_out;
  double* wsd = (double*)d_ws;
  float* corr = (float*)(wsd + WS_DEND);               // [16384]
  float* pc   = corr + AN * AN;                        // [128*128]
  float* pdg  = pc + NB_GRAM * AN;                     // [128*128]
  float* pg   = pdg + NB_GRAM * AN;                    // [128*16384]

  k_main<<<NB_WORK, 256, 0, stream>>>(x, wsd, pc, pdg, pg);
  k_fold<<<65, 256, 0, stream>>>(pc, pdg, pg, wsd, corr);
  k_spec_tail<<<1, 256, 0, stream>>>(x, pos, w1, b1, gamma, beta, w2, b2,
                                     w3, b3, wsd, corr, out);
}